// Round 4
// baseline (164.035 us; speedup 1.0000x reference)
//
#include <hip/hip_runtime.h>

// DialogueGCN on MI355X — round 3 (round-2 + d_out cast fix).
// GEMM-first restructure (gather commutes with GEMM):
//   xW  = x @ [W0-W1 | W2-W3 | W1+W3 | W_aggr]   (K=512, N=2048, bf16)
//   y   = x @ w_att  (split-bf16, K=1536, fp32)  — fused into same fat dispatch
//   h1  = relu( bandgather(xW, attn) )           (scores+softmax fused here)
//   h1W = h1 @ [..layer2 mix..]                  (K=512, N=2048, bf16)
//   out = relu( bandgather(h1W, attn) )          fp32
// All GEMMs use the 128x128-tile m97 structure (BK=32, 4 waves, global_load_lds).

#define NN 4096

typedef __bf16 bf16x8 __attribute__((ext_vector_type(8)));
typedef float f32x4 __attribute__((ext_vector_type(4)));
typedef unsigned short u16;
typedef unsigned int u32;

__device__ __forceinline__ u16 f2bf(float f) {
  unsigned u = __float_as_uint(f);
  unsigned r = u + 0x7FFFu + ((u >> 16) & 1u);
  return (u16)(r >> 16);
}
__device__ __forceinline__ float bf2f(u16 h) {
  return __uint_as_float(((unsigned)h) << 16);
}
__device__ __forceinline__ u32 packbf(float a, float b) {
  return (u32)f2bf(a) | ((u32)f2bf(b) << 16);
}

__device__ __forceinline__ void gload_lds16(const u16* g, u16* l) {
  __builtin_amdgcn_global_load_lds(
      (const __attribute__((address_space(1))) void*)g,
      (__attribute__((address_space(3))) void*)l, 16, 0, 0);
}

// ---------------- fused prep ----------------
// seg A (blocks [0,8192)):     x -> Aatt [N][1536] = [hi | lo | hi]
// seg B (blocks [8192,9216)):  w_att -> Batt [512 j][1536] = [hi|hi|lo] of w_att[:,j]
// seg W (blocks [9216,17408)): Wt[2048 j][512 k] for layers 1,2; out-col j panels:
//   p0: gc0-gc1, p1: gc2-gc3, p2: gc1+gc3, p3: w_aggr  (all indexed [k][jj])
__global__ void prep_all(const float* __restrict__ x, const float* __restrict__ w_att,
                         const float* __restrict__ w_gc1, const float* __restrict__ w_aggr1,
                         const float* __restrict__ w_gc2, const float* __restrict__ w_aggr2,
                         u16* __restrict__ Aatt, u16* __restrict__ Batt,
                         u16* __restrict__ Wt1, u16* __restrict__ Wt2) {
  const int b = blockIdx.x, tid = threadIdx.x;
  if (b < 8192) {
    int idx = b * 256 + tid;
    int r = idx >> 9, c = idx & 511;
    float v = x[idx];
    u16 hi = f2bf(v), lo = f2bf(v - bf2f(hi));
    u16* row = Aatt + (size_t)r * 1536;
    row[c] = hi; row[512 + c] = lo; row[1024 + c] = hi;
  } else if (b < 9216) {
    int idx = (b - 8192) * 256 + tid;
    int j = idx >> 9, e = idx & 511;
    float v = w_att[(size_t)e * 512 + j];
    u16 hi = f2bf(v), lo = f2bf(v - bf2f(hi));
    u16* row = Batt + (size_t)j * 1536;
    row[e] = hi; row[512 + e] = hi; row[1024 + e] = lo;
  } else {
    int lay = (b >= 13312);
    int idx = (b - (lay ? 13312 : 9216)) * 256 + tid;  // over 2048*512
    const float* g = lay ? w_gc2 : w_gc1;
    const float* wa = lay ? w_aggr2 : w_aggr1;
    u16* Wt = lay ? Wt2 : Wt1;
    int j = idx >> 9, k = idx & 511;
    int p = j >> 9, jj = j & 511;
    size_t o = (size_t)k * 512 + jj;
    float v;
    if (p == 0)      v = g[o] - g[262144 + o];
    else if (p == 1) v = g[524288 + o] - g[786432 + o];
    else if (p == 2) v = g[262144 + o] + g[786432 + o];
    else             v = wa[o];
    Wt[(size_t)j * 512 + k] = f2bf(v);
  }
}

// ---------------- 128x128 GEMM core (m97 structure) ----------------
__device__ __forceinline__ void gemm_core(const u16* __restrict__ A, const u16* __restrict__ Bt,
                                          int K, int lda, int ldb, size_t bm, size_t bn,
                                          u16* As, u16* Bs, f32x4 (&acc)[4][4]) {
  const int tid = threadIdx.x;
  const int lane = tid & 63;
  const int wave = tid >> 6;
  const int wr = wave >> 1, wc = wave & 1;
  const int i0 = tid * 8, i1 = i0 + 2048;
  const int ar0 = i0 >> 5, ac0 = i0 & 31;
  const int ar1 = i1 >> 5, ac1 = i1 & 31;
  const int kb = (lane >> 4) * 8;
  const int arow = wr * 64 + (lane & 15);
  const int bcol = wc * 64 + (lane & 15);

  for (int k0 = 0; k0 < K; k0 += 32) {
    gload_lds16(A + (bm + ar0) * lda + k0 + ac0, &As[i0]);
    gload_lds16(A + (bm + ar1) * lda + k0 + ac1, &As[i1]);
    gload_lds16(Bt + (bn + ar0) * ldb + k0 + ac0, &Bs[i0]);
    gload_lds16(Bt + (bn + ar1) * ldb + k0 + ac1, &Bs[i1]);
    asm volatile("s_waitcnt vmcnt(0)" ::: "memory");
    __syncthreads();
    bf16x8 af[4], bfr[4];
#pragma unroll
    for (int i = 0; i < 4; ++i) {
      af[i] = *(const bf16x8*)&As[(arow + i * 16) * 32 + kb];
      bfr[i] = *(const bf16x8*)&Bs[(bcol + i * 16) * 32 + kb];
    }
#pragma unroll
    for (int i = 0; i < 4; ++i)
#pragma unroll
      for (int j = 0; j < 4; ++j)
        acc[i][j] = __builtin_amdgcn_mfma_f32_16x16x32_bf16(af[i], bfr[j], acc[i][j], 0, 0, 0);
    __syncthreads();
  }
}

// fat GEMM: blockIdx.x < 4 -> y panel (split-bf16, K=1536, f32 out);
//           else            -> xW panel (K=512, bf16 out)
__global__ __launch_bounds__(256, 2) void fat_gemm(const u16* __restrict__ Aatt,
                                                   const u16* __restrict__ Wt1,
                                                   const u16* __restrict__ Batt,
                                                   u16* __restrict__ xW, float* __restrict__ y) {
  __shared__ u16 As[128 * 32];
  __shared__ u16 Bs[128 * 32];
  f32x4 acc[4][4] = {};
  const int tid = threadIdx.x;
  const int lane = tid & 63;
  const int wave = tid >> 6;
  const int wr = wave >> 1, wc = wave & 1;
  const size_t bm = (size_t)blockIdx.y * 128;
  const bool yp = blockIdx.x < 4;
  const size_t bn = yp ? (size_t)blockIdx.x * 128 : (size_t)(blockIdx.x - 4) * 128;

  if (yp)
    gemm_core(Aatt, Batt, 1536, 1536, 1536, bm, bn, As, Bs, acc);
  else
    gemm_core(Aatt, Wt1, 512, 1536, 512, bm, bn, As, Bs, acc);

  const size_t crow = bm + wr * 64 + ((lane >> 4) * 4);
  const size_t ccol = bn + wc * 64 + (lane & 15);
#pragma unroll
  for (int i = 0; i < 4; ++i)
#pragma unroll
    for (int j = 0; j < 4; ++j)
#pragma unroll
      for (int b = 0; b < 4; ++b) {
        size_t r = crow + i * 16 + b, c = ccol + j * 16;
        if (yp)
          y[r * 512 + c] = acc[i][j][b];
        else
          xW[r * 2048 + c] = f2bf(acc[i][j][b]);
      }
}

// layer-2 GEMM: h1W = h1 @ Wt2^T, K=512, bf16 out, ldc=2048
__global__ __launch_bounds__(256, 2) void gemm_l2(const u16* __restrict__ h1,
                                                  const u16* __restrict__ Wt2,
                                                  u16* __restrict__ h1W) {
  __shared__ u16 As[128 * 32];
  __shared__ u16 Bs[128 * 32];
  f32x4 acc[4][4] = {};
  const int tid = threadIdx.x;
  const int lane = tid & 63;
  const int wave = tid >> 6;
  const int wr = wave >> 1, wc = wave & 1;
  const size_t bm = (size_t)blockIdx.y * 128;
  const size_t bn = (size_t)blockIdx.x * 128;
  gemm_core(h1, Wt2, 512, 512, 512, bm, bn, As, Bs, acc);
  const size_t crow = bm + wr * 64 + ((lane >> 4) * 4);
  const size_t ccol = bn + wc * 64 + (lane & 15);
#pragma unroll
  for (int i = 0; i < 4; ++i)
#pragma unroll
    for (int j = 0; j < 4; ++j)
#pragma unroll
      for (int b = 0; b < 4; ++b) {
        size_t r = crow + i * 16 + b, c = ccol + j * 16;
        h1W[r * 2048 + c] = f2bf(acc[i][j][b]);
      }
}

// ---------------- gather1: scores + softmax + banded aggregate + relu ----------------
__global__ void gather1(const float* __restrict__ x, const float* __restrict__ y,
                        const u16* __restrict__ xW, const int* __restrict__ spk,
                        float* __restrict__ attn, u16* __restrict__ h1) {
  const int n = blockIdx.x, tid = threadIdx.x;
  __shared__ float ys[512];
  __shared__ float sc[21];
  __shared__ float av[21];
  __shared__ int sps[21];
  ys[tid] = y[(size_t)n * 512 + tid];
  ys[tid + 256] = y[(size_t)n * 512 + tid + 256];
  if (tid < 21) {
    int m = n + tid - 10;
    sps[tid] = (0 <= m && m < NN) ? spk[m] : -9;
  }
  __syncthreads();
  const int wave = tid >> 6, lane = tid & 63;
  for (int w = wave; w < 21; w += 4) {
    int m = n + w - 10;
    float s = 0.f;
    if (0 <= m && m < NN) {
      const float* xm = x + (size_t)m * 512;
      float p = 0.f;
#pragma unroll
      for (int i = 0; i < 8; ++i) p += xm[lane + i * 64] * ys[lane + i * 64];
#pragma unroll
      for (int off = 32; off; off >>= 1) p += __shfl_xor(p, off, 64);
      s = p;
    }
    if (lane == 0) sc[w] = s;
  }
  __syncthreads();
  if (tid < 64) {
    float v = (tid < 21) ? sc[tid] : -1e30f;
    float mx = v;
#pragma unroll
    for (int off = 32; off; off >>= 1) mx = fmaxf(mx, __shfl_xor(mx, off, 64));
    float e = (tid < 21) ? __expf(v - mx) : 0.f;
    float sum = e;
#pragma unroll
    for (int off = 32; off; off >>= 1) sum += __shfl_xor(sum, off, 64);
    if (tid < 21) {
      int m = n + tid - 10;
      float a = (0 <= m && m < NN) ? (e / sum) : 0.f;
      av[tid] = a;
      attn[(size_t)n * 24 + tid] = a;
    }
  }
  __syncthreads();
  const int mysp = spk[n];
  const u32* self = (const u32*)(xW + (size_t)n * 2048);
  u32 hv = self[768 + tid];
  float a0 = bf2f((u16)hv), a1 = bf2f((u16)(hv >> 16));
  for (int w = 0; w < 21; ++w) {
    int m = n + w - 10;
    if (m < 0 || m >= NN) continue;
    float a = av[w];
    const u32* row = (const u32*)(xW + (size_t)m * 2048);
    u32 vp = row[tid], vs = row[256 + tid], va = row[512 + tid];
    float ap = (m >= n) ? a : 0.f;
    float as = (sps[w] == mysp) ? a : 0.f;
    a0 += ap * bf2f((u16)vp) + as * bf2f((u16)vs) + a * bf2f((u16)va);
    a1 += ap * bf2f((u16)(vp >> 16)) + as * bf2f((u16)(vs >> 16)) + a * bf2f((u16)(va >> 16));
  }
  ((u32*)(h1 + (size_t)n * 512))[tid] = packbf(fmaxf(a0, 0.f), fmaxf(a1, 0.f));
}

// ---------------- gather2: banded aggregate + relu -> fp32 out ----------------
__global__ void gather2(const u16* __restrict__ h1W, const float* __restrict__ attn,
                        const int* __restrict__ spk, float* __restrict__ out) {
  const int n = blockIdx.x, tid = threadIdx.x;
  __shared__ float av[21];
  __shared__ int sps[21];
  if (tid < 21) {
    int m = n + tid - 10;
    av[tid] = attn[(size_t)n * 24 + tid];
    sps[tid] = (0 <= m && m < NN) ? spk[m] : -9;
  }
  __syncthreads();
  const int mysp = spk[n];
  const u32* self = (const u32*)(h1W + (size_t)n * 2048);
  u32 hv = self[768 + tid];
  float a0 = bf2f((u16)hv), a1 = bf2f((u16)(hv >> 16));
  for (int w = 0; w < 21; ++w) {
    int m = n + w - 10;
    if (m < 0 || m >= NN) continue;
    float a = av[w];
    const u32* row = (const u32*)(h1W + (size_t)m * 2048);
    u32 vp = row[tid], vs = row[256 + tid], va = row[512 + tid];
    float ap = (m >= n) ? a : 0.f;
    float as = (sps[w] == mysp) ? a : 0.f;
    a0 += ap * bf2f((u16)vp) + as * bf2f((u16)vs) + a * bf2f((u16)va);
    a1 += ap * bf2f((u16)(vp >> 16)) + as * bf2f((u16)(vs >> 16)) + a * bf2f((u16)(va >> 16));
  }
  float* o = out + (size_t)n * 512 + tid * 2;
  o[0] = fmaxf(a0, 0.f);
  o[1] = fmaxf(a1, 0.f);
}

// ---------------- launch ----------------
extern "C" void kernel_launch(void* const* d_in, const int* in_sizes, int n_in,
                              void* d_out, int out_size, void* d_ws, size_t ws_size,
                              hipStream_t stream) {
  const float* x = (const float*)d_in[0];
  const int* spk = (const int*)d_in[1];
  const float* w_gc1 = (const float*)d_in[2];
  const float* w_gc2 = (const float*)d_in[3];
  const float* w_att = (const float*)d_in[4];
  const float* w_aggr1 = (const float*)d_in[5];
  const float* w_aggr2 = (const float*)d_in[6];

  char* p = (char*)d_ws;
  u16* Aatt = (u16*)p;  p += (size_t)NN * 1536 * 2;    // 12.6 MB
  u16* Batt = (u16*)p;  p += (size_t)512 * 1536 * 2;   // 1.6 MB
  u16* Wt1 = (u16*)p;   p += (size_t)2048 * 512 * 2;   // 2.1 MB
  u16* Wt2 = (u16*)p;   p += (size_t)2048 * 512 * 2;   // 2.1 MB
  float* y = (float*)p; p += (size_t)NN * 512 * 4;     // 8.4 MB
  float* attn = (float*)p; p += (size_t)NN * 24 * 4;   // 0.4 MB
  u16* xW = (u16*)p;    p += (size_t)NN * 2048 * 2;    // 16.8 MB
  u16* h1 = (u16*)p;    p += (size_t)NN * 512 * 2;     // 4.2 MB
  u16* h1W = (u16*)p;   p += (size_t)NN * 2048 * 2;    // 16.8 MB (~65 MB total)

  prep_all<<<17408, 256, 0, stream>>>(x, w_att, w_gc1, w_aggr1, w_gc2, w_aggr2,
                                      Aatt, Batt, Wt1, Wt2);

  // y (4 col-blocks, scheduled first) + xW (16 col-blocks), M=4096
  fat_gemm<<<dim3(20, 32), 256, 0, stream>>>(Aatt, Wt1, Batt, xW, y);

  gather1<<<NN, 256, 0, stream>>>(x, y, xW, spk, attn, h1);

  gemm_l2<<<dim3(16, 32), 256, 0, stream>>>(h1, Wt2, h1W);

  gather2<<<NN, 256, 0, stream>>>(h1W, attn, spk, (float*)d_out);
}

// Round 5
// 121.445 us; speedup vs baseline: 1.3507x; 1.3507x over previous
//
#include <hip/hip_runtime.h>

// DialogueGCN on MI355X — round 4 = round 3 + XCD-aware block swizzle in gathers.
// gather1 was 50.6us with 157MB FETCH (8x over-fetch: band halos re-streamed per XCD).
// n = (bid%8)*512 + bid/8 gives each XCD a contiguous 512-row slice -> L2-served band.

#define NN 4096

typedef __bf16 bf16x8 __attribute__((ext_vector_type(8)));
typedef float f32x4 __attribute__((ext_vector_type(4)));
typedef unsigned short u16;
typedef unsigned int u32;

__device__ __forceinline__ u16 f2bf(float f) {
  unsigned u = __float_as_uint(f);
  unsigned r = u + 0x7FFFu + ((u >> 16) & 1u);
  return (u16)(r >> 16);
}
__device__ __forceinline__ float bf2f(u16 h) {
  return __uint_as_float(((unsigned)h) << 16);
}
__device__ __forceinline__ u32 packbf(float a, float b) {
  return (u32)f2bf(a) | ((u32)f2bf(b) << 16);
}

__device__ __forceinline__ void gload_lds16(const u16* g, u16* l) {
  __builtin_amdgcn_global_load_lds(
      (const __attribute__((address_space(1))) void*)g,
      (__attribute__((address_space(3))) void*)l, 16, 0, 0);
}

// ---------------- fused prep ----------------
__global__ void prep_all(const float* __restrict__ x, const float* __restrict__ w_att,
                         const float* __restrict__ w_gc1, const float* __restrict__ w_aggr1,
                         const float* __restrict__ w_gc2, const float* __restrict__ w_aggr2,
                         u16* __restrict__ Aatt, u16* __restrict__ Batt,
                         u16* __restrict__ Wt1, u16* __restrict__ Wt2) {
  const int b = blockIdx.x, tid = threadIdx.x;
  if (b < 8192) {
    int idx = b * 256 + tid;
    int r = idx >> 9, c = idx & 511;
    float v = x[idx];
    u16 hi = f2bf(v), lo = f2bf(v - bf2f(hi));
    u16* row = Aatt + (size_t)r * 1536;
    row[c] = hi; row[512 + c] = lo; row[1024 + c] = hi;
  } else if (b < 9216) {
    int idx = (b - 8192) * 256 + tid;
    int j = idx >> 9, e = idx & 511;
    float v = w_att[(size_t)e * 512 + j];
    u16 hi = f2bf(v), lo = f2bf(v - bf2f(hi));
    u16* row = Batt + (size_t)j * 1536;
    row[e] = hi; row[512 + e] = hi; row[1024 + e] = lo;
  } else {
    int lay = (b >= 13312);
    int idx = (b - (lay ? 13312 : 9216)) * 256 + tid;  // over 2048*512
    const float* g = lay ? w_gc2 : w_gc1;
    const float* wa = lay ? w_aggr2 : w_aggr1;
    u16* Wt = lay ? Wt2 : Wt1;
    int j = idx >> 9, k = idx & 511;
    int p = j >> 9, jj = j & 511;
    size_t o = (size_t)k * 512 + jj;
    float v;
    if (p == 0)      v = g[o] - g[262144 + o];
    else if (p == 1) v = g[524288 + o] - g[786432 + o];
    else if (p == 2) v = g[262144 + o] + g[786432 + o];
    else             v = wa[o];
    Wt[(size_t)j * 512 + k] = f2bf(v);
  }
}

// ---------------- 128x128 GEMM core (m97 structure) ----------------
__device__ __forceinline__ void gemm_core(const u16* __restrict__ A, const u16* __restrict__ Bt,
                                          int K, int lda, int ldb, size_t bm, size_t bn,
                                          u16* As, u16* Bs, f32x4 (&acc)[4][4]) {
  const int tid = threadIdx.x;
  const int lane = tid & 63;
  const int wave = tid >> 6;
  const int wr = wave >> 1, wc = wave & 1;
  const int i0 = tid * 8, i1 = i0 + 2048;
  const int ar0 = i0 >> 5, ac0 = i0 & 31;
  const int ar1 = i1 >> 5, ac1 = i1 & 31;
  const int kb = (lane >> 4) * 8;
  const int arow = wr * 64 + (lane & 15);
  const int bcol = wc * 64 + (lane & 15);

  for (int k0 = 0; k0 < K; k0 += 32) {
    gload_lds16(A + (bm + ar0) * lda + k0 + ac0, &As[i0]);
    gload_lds16(A + (bm + ar1) * lda + k0 + ac1, &As[i1]);
    gload_lds16(Bt + (bn + ar0) * ldb + k0 + ac0, &Bs[i0]);
    gload_lds16(Bt + (bn + ar1) * ldb + k0 + ac1, &Bs[i1]);
    asm volatile("s_waitcnt vmcnt(0)" ::: "memory");
    __syncthreads();
    bf16x8 af[4], bfr[4];
#pragma unroll
    for (int i = 0; i < 4; ++i) {
      af[i] = *(const bf16x8*)&As[(arow + i * 16) * 32 + kb];
      bfr[i] = *(const bf16x8*)&Bs[(bcol + i * 16) * 32 + kb];
    }
#pragma unroll
    for (int i = 0; i < 4; ++i)
#pragma unroll
      for (int j = 0; j < 4; ++j)
        acc[i][j] = __builtin_amdgcn_mfma_f32_16x16x32_bf16(af[i], bfr[j], acc[i][j], 0, 0, 0);
    __syncthreads();
  }
}

// fat GEMM: blockIdx.x < 4 -> y panel (split-bf16, K=1536, f32 out);
//           else            -> xW panel (K=512, bf16 out)
__global__ __launch_bounds__(256, 2) void fat_gemm(const u16* __restrict__ Aatt,
                                                   const u16* __restrict__ Wt1,
                                                   const u16* __restrict__ Batt,
                                                   u16* __restrict__ xW, float* __restrict__ y) {
  __shared__ u16 As[128 * 32];
  __shared__ u16 Bs[128 * 32];
  f32x4 acc[4][4] = {};
  const int tid = threadIdx.x;
  const int lane = tid & 63;
  const int wave = tid >> 6;
  const int wr = wave >> 1, wc = wave & 1;
  const size_t bm = (size_t)blockIdx.y * 128;
  const bool yp = blockIdx.x < 4;
  const size_t bn = yp ? (size_t)blockIdx.x * 128 : (size_t)(blockIdx.x - 4) * 128;

  if (yp)
    gemm_core(Aatt, Batt, 1536, 1536, 1536, bm, bn, As, Bs, acc);
  else
    gemm_core(Aatt, Wt1, 512, 1536, 512, bm, bn, As, Bs, acc);

  const size_t crow = bm + wr * 64 + ((lane >> 4) * 4);
  const size_t ccol = bn + wc * 64 + (lane & 15);
#pragma unroll
  for (int i = 0; i < 4; ++i)
#pragma unroll
    for (int j = 0; j < 4; ++j)
#pragma unroll
      for (int b = 0; b < 4; ++b) {
        size_t r = crow + i * 16 + b, c = ccol + j * 16;
        if (yp)
          y[r * 512 + c] = acc[i][j][b];
        else
          xW[r * 2048 + c] = f2bf(acc[i][j][b]);
      }
}

// layer-2 GEMM: h1W = h1 @ Wt2^T, K=512, bf16 out, ldc=2048
__global__ __launch_bounds__(256, 2) void gemm_l2(const u16* __restrict__ h1,
                                                  const u16* __restrict__ Wt2,
                                                  u16* __restrict__ h1W) {
  __shared__ u16 As[128 * 32];
  __shared__ u16 Bs[128 * 32];
  f32x4 acc[4][4] = {};
  const int tid = threadIdx.x;
  const int lane = tid & 63;
  const int wave = tid >> 6;
  const int wr = wave >> 1, wc = wave & 1;
  const size_t bm = (size_t)blockIdx.y * 128;
  const size_t bn = (size_t)blockIdx.x * 128;
  gemm_core(h1, Wt2, 512, 512, 512, bm, bn, As, Bs, acc);
  const size_t crow = bm + wr * 64 + ((lane >> 4) * 4);
  const size_t ccol = bn + wc * 64 + (lane & 15);
#pragma unroll
  for (int i = 0; i < 4; ++i)
#pragma unroll
    for (int j = 0; j < 4; ++j)
#pragma unroll
      for (int b = 0; b < 4; ++b) {
        size_t r = crow + i * 16 + b, c = ccol + j * 16;
        h1W[r * 2048 + c] = f2bf(acc[i][j][b]);
      }
}

// XCD-contiguous row mapping: 4096 blocks, 8 XCDs, block b -> XCD b%8.
__device__ __forceinline__ int xcd_row(int b) { return (b & 7) * 512 + (b >> 3); }

// ---------------- gather1: scores + softmax + banded aggregate + relu ----------------
__global__ void gather1(const float* __restrict__ x, const float* __restrict__ y,
                        const u16* __restrict__ xW, const int* __restrict__ spk,
                        float* __restrict__ attn, u16* __restrict__ h1) {
  const int n = xcd_row(blockIdx.x);
  const int tid = threadIdx.x;
  __shared__ float ys[512];
  __shared__ float sc[21];
  __shared__ float av[21];
  __shared__ int sps[21];
  ys[tid] = y[(size_t)n * 512 + tid];
  ys[tid + 256] = y[(size_t)n * 512 + tid + 256];
  if (tid < 21) {
    int m = n + tid - 10;
    sps[tid] = (0 <= m && m < NN) ? spk[m] : -9;
  }
  __syncthreads();
  const int wave = tid >> 6, lane = tid & 63;
  for (int w = wave; w < 21; w += 4) {
    int m = n + w - 10;
    float s = 0.f;
    if (0 <= m && m < NN) {
      const float* xm = x + (size_t)m * 512;
      float p = 0.f;
#pragma unroll
      for (int i = 0; i < 8; ++i) p += xm[lane + i * 64] * ys[lane + i * 64];
#pragma unroll
      for (int off = 32; off; off >>= 1) p += __shfl_xor(p, off, 64);
      s = p;
    }
    if (lane == 0) sc[w] = s;
  }
  __syncthreads();
  if (tid < 64) {
    float v = (tid < 21) ? sc[tid] : -1e30f;
    float mx = v;
#pragma unroll
    for (int off = 32; off; off >>= 1) mx = fmaxf(mx, __shfl_xor(mx, off, 64));
    float e = (tid < 21) ? __expf(v - mx) : 0.f;
    float sum = e;
#pragma unroll
    for (int off = 32; off; off >>= 1) sum += __shfl_xor(sum, off, 64);
    if (tid < 21) {
      int m = n + tid - 10;
      float a = (0 <= m && m < NN) ? (e / sum) : 0.f;
      av[tid] = a;
      attn[(size_t)n * 24 + tid] = a;
    }
  }
  __syncthreads();
  const int mysp = spk[n];
  const u32* self = (const u32*)(xW + (size_t)n * 2048);
  u32 hv = self[768 + tid];
  float a0 = bf2f((u16)hv), a1 = bf2f((u16)(hv >> 16));
  for (int w = 0; w < 21; ++w) {
    int m = n + w - 10;
    if (m < 0 || m >= NN) continue;
    float a = av[w];
    const u32* row = (const u32*)(xW + (size_t)m * 2048);
    u32 vp = row[tid], vs = row[256 + tid], va = row[512 + tid];
    float ap = (m >= n) ? a : 0.f;
    float as = (sps[w] == mysp) ? a : 0.f;
    a0 += ap * bf2f((u16)vp) + as * bf2f((u16)vs) + a * bf2f((u16)va);
    a1 += ap * bf2f((u16)(vp >> 16)) + as * bf2f((u16)(vs >> 16)) + a * bf2f((u16)(va >> 16));
  }
  ((u32*)(h1 + (size_t)n * 512))[tid] = packbf(fmaxf(a0, 0.f), fmaxf(a1, 0.f));
}

// ---------------- gather2: banded aggregate + relu -> fp32 out ----------------
__global__ void gather2(const u16* __restrict__ h1W, const float* __restrict__ attn,
                        const int* __restrict__ spk, float* __restrict__ out) {
  const int n = xcd_row(blockIdx.x);
  const int tid = threadIdx.x;
  __shared__ float av[21];
  __shared__ int sps[21];
  if (tid < 21) {
    int m = n + tid - 10;
    av[tid] = attn[(size_t)n * 24 + tid];
    sps[tid] = (0 <= m && m < NN) ? spk[m] : -9;
  }
  __syncthreads();
  const int mysp = spk[n];
  const u32* self = (const u32*)(h1W + (size_t)n * 2048);
  u32 hv = self[768 + tid];
  float a0 = bf2f((u16)hv), a1 = bf2f((u16)(hv >> 16));
  for (int w = 0; w < 21; ++w) {
    int m = n + w - 10;
    if (m < 0 || m >= NN) continue;
    float a = av[w];
    const u32* row = (const u32*)(h1W + (size_t)m * 2048);
    u32 vp = row[tid], vs = row[256 + tid], va = row[512 + tid];
    float ap = (m >= n) ? a : 0.f;
    float as = (sps[w] == mysp) ? a : 0.f;
    a0 += ap * bf2f((u16)vp) + as * bf2f((u16)vs) + a * bf2f((u16)va);
    a1 += ap * bf2f((u16)(vp >> 16)) + as * bf2f((u16)(vs >> 16)) + a * bf2f((u16)(va >> 16));
  }
  float* o = out + (size_t)n * 512 + tid * 2;
  o[0] = fmaxf(a0, 0.f);
  o[1] = fmaxf(a1, 0.f);
}

// ---------------- launch ----------------
extern "C" void kernel_launch(void* const* d_in, const int* in_sizes, int n_in,
                              void* d_out, int out_size, void* d_ws, size_t ws_size,
                              hipStream_t stream) {
  const float* x = (const float*)d_in[0];
  const int* spk = (const int*)d_in[1];
  const float* w_gc1 = (const float*)d_in[2];
  const float* w_gc2 = (const float*)d_in[3];
  const float* w_att = (const float*)d_in[4];
  const float* w_aggr1 = (const float*)d_in[5];
  const float* w_aggr2 = (const float*)d_in[6];

  char* p = (char*)d_ws;
  u16* Aatt = (u16*)p;  p += (size_t)NN * 1536 * 2;    // 12.6 MB
  u16* Batt = (u16*)p;  p += (size_t)512 * 1536 * 2;   // 1.6 MB
  u16* Wt1 = (u16*)p;   p += (size_t)2048 * 512 * 2;   // 2.1 MB
  u16* Wt2 = (u16*)p;   p += (size_t)2048 * 512 * 2;   // 2.1 MB
  float* y = (float*)p; p += (size_t)NN * 512 * 4;     // 8.4 MB
  float* attn = (float*)p; p += (size_t)NN * 24 * 4;   // 0.4 MB
  u16* xW = (u16*)p;    p += (size_t)NN * 2048 * 2;    // 16.8 MB
  u16* h1 = (u16*)p;    p += (size_t)NN * 512 * 2;     // 4.2 MB
  u16* h1W = (u16*)p;   p += (size_t)NN * 2048 * 2;    // 16.8 MB (~65 MB total)

  prep_all<<<17408, 256, 0, stream>>>(x, w_att, w_gc1, w_aggr1, w_gc2, w_aggr2,
                                      Aatt, Batt, Wt1, Wt2);

  // y (4 col-blocks, scheduled first) + xW (16 col-blocks), M=4096
  fat_gemm<<<dim3(20, 32), 256, 0, stream>>>(Aatt, Wt1, Batt, xW, y);

  gather1<<<NN, 256, 0, stream>>>(x, y, xW, spk, attn, h1);

  gemm_l2<<<dim3(16, 32), 256, 0, stream>>>(h1, Wt2, h1W);

  gather2<<<NN, 256, 0, stream>>>(h1W, attn, spk, (float*)d_out);
}